// Round 5
// baseline (243.566 us; speedup 1.0000x reference)
//
#include <hip/hip_runtime.h>
#include <hip/hip_bf16.h>
#include <stdint.h>

// Problem constants: B=4, deep_C=256, shallow_C=64, H=W=64, N=4096, qk_C=16.
#define LOG2E 1.44269504088896340736f

typedef __bf16 bf16x8 __attribute__((ext_vector_type(8)));
typedef float  f32x16 __attribute__((ext_vector_type(16)));

__device__ __forceinline__ uint32_t pack_bf2(float a, float b) {
    __bf16 ba = (__bf16)a;  // RNE
    __bf16 bb = (__bf16)b;
    uint16_t ua = __builtin_bit_cast(uint16_t, ba);
    uint16_t ub = __builtin_bit_cast(uint16_t, bb);
    return (uint32_t)ua | ((uint32_t)ub << 16);
}

// ---------------- Fused prepass: qk (blocks 0..63) + vconv (64..2111) ----
// qk first so its long-latency 64-block phase overlaps vconv instead of
// trailing it.
// Vb unit (16 B = 8 keys x 1 chan): gid = (((b*8+ct)*256+kb)*2+h1)*32+c
//   holds deep[b][ct*32+c][kb*16+h1*8 .. +7] as bf16.
// Qb rows: [b][n][32 bf16] = [hi c0..15 | lo c0..15], q PRE-SCALED by LOG2E.
// Kb2 units: addr_u16 = b*131072 + (n>>5)*1024 + s*512 + (h1*32+(n&31))*8,
//   s=0 hi / 1 lo  (a wave reads 1 KB contiguous per frag pair).
__global__ void __launch_bounds__(256) prepass(
    const float* __restrict__ deep, const float* __restrict__ shallow,
    const float* __restrict__ Wq, const float* __restrict__ bq,
    const float* __restrict__ Wk, const float* __restrict__ bk,
    uint16_t* __restrict__ Vb, uint16_t* __restrict__ Qb,
    uint16_t* __restrict__ Kb2) {
    const int blk = blockIdx.x;
    if (blk < 64) {
        int gid = blk * 256 + threadIdx.x;  // 0..16383 = b*4096+n
        int b = gid >> 12;
        int n = gid & 4095;
        const float* sp = shallow + (size_t)b * 64 * 4096 + n;
        float q[16], k[16];
#pragma unroll
        for (int o = 0; o < 16; ++o) { q[o] = bq[o]; k[o] = bk[o]; }
#pragma unroll 4
        for (int c = 0; c < 64; ++c) {
            float s = sp[(size_t)c * 4096];
#pragma unroll
            for (int o = 0; o < 16; ++o) {
                q[o] = fmaf(Wq[o * 64 + c], s, q[o]);
                k[o] = fmaf(Wk[o * 64 + c], s, k[o]);
            }
        }
        uint16_t* qr = Qb + (size_t)gid * 32;
        float klo[16];
#pragma unroll
        for (int o = 0; o < 16; ++o) {
            float qs = q[o] * LOG2E;             // fold log2(e) into Q
            __bf16 qh = (__bf16)qs; float qhf = (float)qh;
            __bf16 ql = (__bf16)(qs - qhf);
            qr[o]      = __builtin_bit_cast(uint16_t, qh);
            qr[16 + o] = __builtin_bit_cast(uint16_t, ql);
            klo[o] = k[o] - (float)((__bf16)k[o]);
        }
        uint16_t* kbase = Kb2 + (size_t)b * 131072 + (size_t)(n >> 5) * 1024
                              + (size_t)(n & 31) * 8;
        *(uint4*)(kbase +   0) = make_uint4(pack_bf2(k[0], k[1]),   pack_bf2(k[2], k[3]),
                                            pack_bf2(k[4], k[5]),   pack_bf2(k[6], k[7]));
        *(uint4*)(kbase + 256) = make_uint4(pack_bf2(k[8], k[9]),   pack_bf2(k[10], k[11]),
                                            pack_bf2(k[12], k[13]), pack_bf2(k[14], k[15]));
        *(uint4*)(kbase + 512) = make_uint4(pack_bf2(klo[0], klo[1]),   pack_bf2(klo[2], klo[3]),
                                            pack_bf2(klo[4], klo[5]),   pack_bf2(klo[6], klo[7]));
        *(uint4*)(kbase + 768) = make_uint4(pack_bf2(klo[8], klo[9]),   pack_bf2(klo[10], klo[11]),
                                            pack_bf2(klo[12], klo[13]), pack_bf2(klo[14], klo[15]));
    } else {
        int gid = (blk - 64) * 256 + threadIdx.x;   // 0..524287
        int c  = gid & 31;
        int h1 = (gid >> 5) & 1;
        int kb = (gid >> 6) & 255;
        int ct = (gid >> 14) & 7;
        int b  = gid >> 17;
        int chan = ct * 32 + c;
        int key  = kb * 16 + h1 * 8;
        const float4* dp = (const float4*)(deep + ((size_t)(b * 256 + chan) * 4096 + key));
        float4 f0 = dp[0], f1 = dp[1];
        ((uint4*)Vb)[gid] = make_uint4(pack_bf2(f0.x, f0.y), pack_bf2(f0.z, f0.w),
                                       pack_bf2(f1.x, f1.y), pack_bf2(f1.z, f1.w));
    }
}

// ---------------- Main fused flash-attention kernel ----------------------
// Grid: 256 blocks x 1024 threads (16 waves, 4/SIMD). Block = (b, 64-query
// tile), all 256 chans. Producer/consumer wave specialization:
//   waves 0-7  (producers): QK^T + max-free softmax for their 32-key slice
//     of superstep ss+1 -> Pl[par^1], Ls[par^1]; K prefetched 1 ss ahead.
//   waves 8-15 (consumers): PV for their 32-chan tile over 256 keys of ss,
//     V register-double-buffered in 8-frag half-chunks (issue one half
//     ahead); per-ss l accumulation; epilogue out = gamma*acc/l + deep.
// One barrier per superstep; producer stalls hide under consumer work and
// vice versa on each SIMD (4 waves/SIMD: 2 producers + 2 consumers).
__global__ void __launch_bounds__(1024, 4) attn_main(
    const uint16_t* __restrict__ Qb, const uint16_t* __restrict__ Kb2,
    const uint16_t* __restrict__ Vb, const float* __restrict__ deep,
    const float* __restrict__ gamma, float* __restrict__ out) {
    const int lane = threadIdx.x & 63;
    const int w    = threadIdx.x >> 6;   // 0..15
    const int col  = lane & 31;
    const int h1   = lane >> 5;
    const bool producer = (w < 8);
    const int  pw = w & 7;               // producer key-slice / consumer chan-tile

    // XCD-locality: one batch per XCD pair (V slice 2 MB < 4 MB L2/XCD).
    const int bid = blockIdx.x;
    const int xcd = bid & 7;
    const int b   = xcd >> 1;
    const int qt  = ((bid >> 3) << 1) + (xcd & 1);   // 0..63
    const int n0q = qt * 64;

    __shared__ uint4 Pl[2][2][16][2][32];  // par, qh, frag, h1', col  = 64 KB
    __shared__ float Ls[2][2][16][32];     // par, qh, pw*2+h1, col    =  8 KB

    // ---- role-specific state ----
    uint4 ubqh[2], ubql[2];                // producer: Q B-frags (log2-scaled)
    uint4 ukh, ukl;                        // producer: K frags (current ss)
    const uint16_t* kbase = nullptr;
    f32x16 acc0, acc1;                     // consumer: out^T accumulators
    float l0, l1;
    const uint16_t* vlane = nullptr;
    uint4 vrA[8], vrB[8];                  // consumer: V half-chunk dbuf

    if (producer) {
#pragma unroll
        for (int qh = 0; qh < 2; ++qh) {
            const uint16_t* qrow = Qb + ((size_t)(b * 4096 + n0q + qh * 32 + col)) * 32;
            ubqh[qh] = *(const uint4*)(qrow + h1 * 8);
            ubql[qh] = *(const uint4*)(qrow + 16 + h1 * 8);
        }
        kbase = Kb2 + (size_t)b * 131072 + (size_t)pw * 1024 + (size_t)lane * 8;
        ukh = *(const uint4*)(kbase);
        ukl = *(const uint4*)(kbase + 512);
    } else {
        vlane = Vb + (size_t)(b * 8 + pw) * 131072
                   + (size_t)h1 * 256 + (size_t)col * 8;
#pragma unroll
        for (int r = 0; r < 16; ++r) { acc0[r] = 0.0f; acc1[r] = 0.0f; }
        l0 = 0.0f; l1 = 0.0f;
    }

    // Producer: QK + softmax for superstep s -> Pl[s&1], Ls[s&1]; prefetch K(s+1).
    auto qk_softmax = [&](int s) {
        const int pr = s & 1;
        bf16x8 akh = __builtin_bit_cast(bf16x8, ukh);
        bf16x8 akl = __builtin_bit_cast(bf16x8, ukl);
        const int sn = (s < 15) ? s + 1 : s;
        uint4 nkh = *(const uint4*)(kbase + (size_t)sn * 8192);
        uint4 nkl = *(const uint4*)(kbase + (size_t)sn * 8192 + 512);
#pragma unroll
        for (int qh = 0; qh < 2; ++qh) {
            bf16x8 bh = __builtin_bit_cast(bf16x8, ubqh[qh]);
            bf16x8 bl = __builtin_bit_cast(bf16x8, ubql[qh]);
            f32x16 e = {0,0,0,0,0,0,0,0,0,0,0,0,0,0,0,0};
            e = __builtin_amdgcn_mfma_f32_32x32x16_bf16(akh, bh, e, 0, 0, 0);
            e = __builtin_amdgcn_mfma_f32_32x32x16_bf16(akl, bh, e, 0, 0, 0);
            e = __builtin_amdgcn_mfma_f32_32x32x16_bf16(akh, bl, e, 0, 0, 0);
            float p[16];
#pragma unroll
            for (int r = 0; r < 16; ++r) p[r] = exp2f(e[r]);  // already log2-scaled
            float t0 = (p[0] + p[1]) + (p[2] + p[3]);
            float t1 = (p[4] + p[5]) + (p[6] + p[7]);
            float t2 = (p[8] + p[9]) + (p[10] + p[11]);
            float t3 = (p[12] + p[13]) + (p[14] + p[15]);
            Ls[pr][qh][pw * 2 + h1][col] = (t0 + t1) + (t2 + t3);
            // direct transposed stores: B-frag[f][h1'][col] words 2h1..2h1+1
            uint32_t pk0 = pack_bf2(p[0],  p[1]),  pk1 = pack_bf2(p[2],  p[3]);
            uint32_t pk2 = pack_bf2(p[4],  p[5]),  pk3 = pack_bf2(p[6],  p[7]);
            uint32_t pk4 = pack_bf2(p[8],  p[9]),  pk5 = pack_bf2(p[10], p[11]);
            uint32_t pk6 = pack_bf2(p[12], p[13]), pk7 = pack_bf2(p[14], p[15]);
            ((uint2*)&Pl[pr][qh][2 * pw    ][0][col])[h1] = make_uint2(pk0, pk1);
            ((uint2*)&Pl[pr][qh][2 * pw    ][1][col])[h1] = make_uint2(pk2, pk3);
            ((uint2*)&Pl[pr][qh][2 * pw + 1][0][col])[h1] = make_uint2(pk4, pk5);
            ((uint2*)&Pl[pr][qh][2 * pw + 1][1][col])[h1] = make_uint2(pk6, pk7);
        }
        ukh = nkh; ukl = nkl;
    };

    // ---- prologue ----
    if (producer) {
        qk_softmax(0);
    } else {
#pragma unroll
        for (int f = 0; f < 8; ++f) vrA[f] = *(const uint4*)(vlane + f * 512);
    }
    __syncthreads();

    // ---- main loop: one barrier per superstep ----
    for (int ss = 0; ss < 16; ++ss) {
        const int par = ss & 1;
        if (producer) {
            if (ss < 15) qk_softmax(ss + 1);
        } else {
            const uint16_t* vss = vlane + (size_t)ss * 8192;
            // half 1: prefetch frags 8-15 of ss; PV frags 0-7 (in vrA)
#pragma unroll
            for (int f = 0; f < 8; ++f)
                vrB[f] = *(const uint4*)(vss + (8 + f) * 512);
            __builtin_amdgcn_s_setprio(1);
#pragma unroll
            for (int f = 0; f < 8; ++f) {
                uint4 pb0 = Pl[par][0][f][h1][col];
                uint4 pb1 = Pl[par][1][f][h1][col];
                acc0 = __builtin_amdgcn_mfma_f32_32x32x16_bf16(
                    __builtin_bit_cast(bf16x8, vrA[f]), __builtin_bit_cast(bf16x8, pb0), acc0, 0, 0, 0);
                acc1 = __builtin_amdgcn_mfma_f32_32x32x16_bf16(
                    __builtin_bit_cast(bf16x8, vrA[f]), __builtin_bit_cast(bf16x8, pb1), acc1, 0, 0, 0);
            }
            __builtin_amdgcn_s_setprio(0);
            // half 2: prefetch frags 0-7 of ss+1; PV frags 8-15 (in vrB)
            const uint16_t* vnx = vlane + (size_t)((ss < 15) ? ss + 1 : ss) * 8192;
#pragma unroll
            for (int f = 0; f < 8; ++f)
                vrA[f] = *(const uint4*)(vnx + f * 512);
            __builtin_amdgcn_s_setprio(1);
#pragma unroll
            for (int f = 0; f < 8; ++f) {
                uint4 pb0 = Pl[par][0][8 + f][h1][col];
                uint4 pb1 = Pl[par][1][8 + f][h1][col];
                acc0 = __builtin_amdgcn_mfma_f32_32x32x16_bf16(
                    __builtin_bit_cast(bf16x8, vrB[f]), __builtin_bit_cast(bf16x8, pb0), acc0, 0, 0, 0);
                acc1 = __builtin_amdgcn_mfma_f32_32x32x16_bf16(
                    __builtin_bit_cast(bf16x8, vrB[f]), __builtin_bit_cast(bf16x8, pb1), acc1, 0, 0, 0);
            }
            __builtin_amdgcn_s_setprio(0);
#pragma unroll
            for (int j = 0; j < 16; ++j) {
                l0 += Ls[par][0][j][col];
                l1 += Ls[par][1][j][col];
            }
        }
        __syncthreads();
    }

    // ---- epilogue (consumers only): out = gamma * acc/l + deep ----
    if (!producer) {
        const float g   = gamma[0];
        const float gr0 = g / l0;
        const float gr1 = g / l1;
#pragma unroll
        for (int r = 0; r < 16; ++r) {
            const int crow = (r & 3) + 8 * (r >> 2) + 4 * h1;
            const int chan = pw * 32 + crow;
            size_t i0 = (size_t)(b * 256 + chan) * 4096 + n0q + col;
            out[i0] = fmaf(gr0, acc0[r], deep[i0]);
            size_t i1 = i0 + 32;
            out[i1] = fmaf(gr1, acc1[r], deep[i1]);
        }
    }
}

extern "C" void kernel_launch(void* const* d_in, const int* in_sizes, int n_in,
                              void* d_out, int out_size, void* d_ws, size_t ws_size,
                              hipStream_t stream) {
    const float* deep    = (const float*)d_in[0];
    const float* shallow = (const float*)d_in[1];
    const float* Wq      = (const float*)d_in[2];
    const float* bq      = (const float*)d_in[3];
    const float* Wk      = (const float*)d_in[4];
    const float* bk      = (const float*)d_in[5];
    const float* gamma   = (const float*)d_in[6];
    float* out = (float*)d_out;

    // ws layout: Vb swizzled bf16 (8 MiB) | Qb (1 MiB) | Kb2 (1 MiB)
    uint16_t* Vb  = (uint16_t*)d_ws;
    uint16_t* Qb  = (uint16_t*)((char*)d_ws + (size_t)8 * 1024 * 1024);
    uint16_t* Kb2 = (uint16_t*)((char*)d_ws + (size_t)9 * 1024 * 1024);

    hipLaunchKernelGGL(prepass, dim3(2112), dim3(256), 0, stream,
                       deep, shallow, Wq, bq, Wk, bk, Vb, Qb, Kb2);
    hipLaunchKernelGGL(attn_main, dim3(256), dim3(1024), 0, stream,
                       Qb, Kb2, Vb, deep, gamma, out);
}

// Round 7
// 86.894 us; speedup vs baseline: 2.8030x; 2.8030x over previous
//
#include <hip/hip_runtime.h>
#include <hip/hip_bf16.h>
#include <stdint.h>

// Problem constants: B=4, deep_C=256, shallow_C=64, H=W=64, N=4096, qk_C=16.
#define LOG2E 1.44269504088896340736f

typedef __bf16 bf16x8 __attribute__((ext_vector_type(8)));
typedef float  f32x16 __attribute__((ext_vector_type(16)));

__device__ __forceinline__ uint32_t pack_bf2(float a, float b) {
    __bf16 ba = (__bf16)a;  // RNE
    __bf16 bb = (__bf16)b;
    uint16_t ua = __builtin_bit_cast(uint16_t, ba);
    uint16_t ub = __builtin_bit_cast(uint16_t, bb);
    return (uint32_t)ua | ((uint32_t)ub << 16);
}

// ---------------- Fused prepass: qk (blocks 0..63) + vconv (64..2111) ----
// Vb unit (16 B = 8 keys x 1 chan): gid = (((b*8+ct)*256+kb)*2+h1)*32+c
//   holds deep[b][ct*32+c][kb*16+h1*8 .. +7] as bf16.
// Qb rows: [b][n][32 bf16] = [hi c0..15 | lo c0..15], q PRE-SCALED by LOG2E.
// Kb2 units: addr_u16 = b*131072 + (n>>5)*1024 + s*512 + (h1*32+(n&31))*8,
//   s=0 hi / 1 lo  (a wave reads 1 KB contiguous per frag pair).
__global__ void __launch_bounds__(256) prepass(
    const float* __restrict__ deep, const float* __restrict__ shallow,
    const float* __restrict__ Wq, const float* __restrict__ bq,
    const float* __restrict__ Wk, const float* __restrict__ bk,
    uint16_t* __restrict__ Vb, uint16_t* __restrict__ Qb,
    uint16_t* __restrict__ Kb2) {
    const int blk = blockIdx.x;
    if (blk < 64) {
        int gid = blk * 256 + threadIdx.x;  // 0..16383 = b*4096+n
        int b = gid >> 12;
        int n = gid & 4095;
        const float* sp = shallow + (size_t)b * 64 * 4096 + n;
        float q[16], k[16];
#pragma unroll
        for (int o = 0; o < 16; ++o) { q[o] = bq[o]; k[o] = bk[o]; }
#pragma unroll 4
        for (int c = 0; c < 64; ++c) {
            float s = sp[(size_t)c * 4096];
#pragma unroll
            for (int o = 0; o < 16; ++o) {
                q[o] = fmaf(Wq[o * 64 + c], s, q[o]);
                k[o] = fmaf(Wk[o * 64 + c], s, k[o]);
            }
        }
        uint16_t* qr = Qb + (size_t)gid * 32;
        float klo[16];
#pragma unroll
        for (int o = 0; o < 16; ++o) {
            float qs = q[o] * LOG2E;             // fold log2(e) into Q
            __bf16 qh = (__bf16)qs; float qhf = (float)qh;
            __bf16 ql = (__bf16)(qs - qhf);
            qr[o]      = __builtin_bit_cast(uint16_t, qh);
            qr[16 + o] = __builtin_bit_cast(uint16_t, ql);
            klo[o] = k[o] - (float)((__bf16)k[o]);
        }
        uint16_t* kbase = Kb2 + (size_t)b * 131072 + (size_t)(n >> 5) * 1024
                              + (size_t)(n & 31) * 8;
        *(uint4*)(kbase +   0) = make_uint4(pack_bf2(k[0], k[1]),   pack_bf2(k[2], k[3]),
                                            pack_bf2(k[4], k[5]),   pack_bf2(k[6], k[7]));
        *(uint4*)(kbase + 256) = make_uint4(pack_bf2(k[8], k[9]),   pack_bf2(k[10], k[11]),
                                            pack_bf2(k[12], k[13]), pack_bf2(k[14], k[15]));
        *(uint4*)(kbase + 512) = make_uint4(pack_bf2(klo[0], klo[1]),   pack_bf2(klo[2], klo[3]),
                                            pack_bf2(klo[4], klo[5]),   pack_bf2(klo[6], klo[7]));
        *(uint4*)(kbase + 768) = make_uint4(pack_bf2(klo[8], klo[9]),   pack_bf2(klo[10], klo[11]),
                                            pack_bf2(klo[12], klo[13]), pack_bf2(klo[14], klo[15]));
    } else {
        int gid = (blk - 64) * 256 + threadIdx.x;   // 0..524287
        int c  = gid & 31;
        int h1 = (gid >> 5) & 1;
        int kb = (gid >> 6) & 255;
        int ct = (gid >> 14) & 7;
        int b  = gid >> 17;
        int chan = ct * 32 + c;
        int key  = kb * 16 + h1 * 8;
        const float4* dp = (const float4*)(deep + ((size_t)(b * 256 + chan) * 4096 + key));
        float4 f0 = dp[0], f1 = dp[1];
        ((uint4*)Vb)[gid] = make_uint4(pack_bf2(f0.x, f0.y), pack_bf2(f0.z, f0.w),
                                       pack_bf2(f1.x, f1.y), pack_bf2(f1.z, f1.w));
    }
}

// ---------------- Main fused flash-attention kernel ----------------------
// Grid: 256 blocks x 1024 threads (16 waves, 4/SIMD). Block = (b, 64-query
// tile), all 256 chans. Producer/consumer wave roles in a SINGLE loop with
// ALL barriers at top level (convergent control flow — r6's per-role loops
// with barriers inside divergent branches raced across graph replays).
// Register budget kept under the 128 cap (r5 spilled ~1 GB): producer
// persistent = Q frags 16 + K prefetch 8; consumer = acc 32 + vr[8] single
// V buffer (refilled mid-region) + l. Union ~120 regs.
//   waves 0-7  (producers): QK^T + max-free softmax for their 32-key slice
//     of superstep ss+1 -> Pl[(ss+1)&1], Ls.
//   waves 8-15 (consumers): PV for their 32-chan tile over 256 keys of ss.
__global__ void __launch_bounds__(1024, 4) attn_main(
    const uint16_t* __restrict__ Qb, const uint16_t* __restrict__ Kb2,
    const uint16_t* __restrict__ Vb, const float* __restrict__ deep,
    const float* __restrict__ gamma, float* __restrict__ out) {
    const int lane = threadIdx.x & 63;
    const int w    = threadIdx.x >> 6;   // 0..15
    const int col  = lane & 31;
    const int h1   = lane >> 5;
    const int pw   = w & 7;              // producer key-slice / consumer chan-tile
    const bool producer = (w < 8);

    // XCD-locality: one batch per XCD pair (V slice 2 MB < 4 MB L2/XCD).
    const int bid = blockIdx.x;
    const int xcd = bid & 7;
    const int b   = xcd >> 1;
    const int qt  = ((bid >> 3) << 1) + (xcd & 1);   // 0..63
    const int n0q = qt * 64;

    __shared__ uint4 Pl[2][2][16][2][32];  // par, qh, frag, h1', col  = 64 KB
    __shared__ float Ls[2][2][16][32];     // par, qh, pw*2+h1, col    =  8 KB

    // ---- role state (kept minimal; allocator unions the two sets) ----
    uint4 ubqh[2], ubql[2];                // producer: Q B-frags (log2-scaled)
    uint4 ukh, ukl;                        // producer: K frags for NEXT produce
    const uint16_t* kbase = nullptr;
    const uint16_t* vlane = nullptr;
    f32x16 acc0 = {0,0,0,0,0,0,0,0,0,0,0,0,0,0,0,0};
    f32x16 acc1 = {0,0,0,0,0,0,0,0,0,0,0,0,0,0,0,0};
    float l0 = 0.0f, l1 = 0.0f;

    // per-qh softmax + pack + LDS store (producer helper)
    auto sm_store = [&](const f32x16& e, int pr, int qh) {
        float p[16];
#pragma unroll
        for (int r = 0; r < 16; ++r) p[r] = exp2f(e[r]);   // Q pre-scaled
        float t0 = (p[0] + p[1]) + (p[2] + p[3]);
        float t1 = (p[4] + p[5]) + (p[6] + p[7]);
        float t2 = (p[8] + p[9]) + (p[10] + p[11]);
        float t3 = (p[12] + p[13]) + (p[14] + p[15]);
        Ls[pr][qh][pw * 2 + h1][col] = (t0 + t1) + (t2 + t3);
        uint32_t pk0 = pack_bf2(p[0],  p[1]),  pk1 = pack_bf2(p[2],  p[3]);
        uint32_t pk2 = pack_bf2(p[4],  p[5]),  pk3 = pack_bf2(p[6],  p[7]);
        uint32_t pk4 = pack_bf2(p[8],  p[9]),  pk5 = pack_bf2(p[10], p[11]);
        uint32_t pk6 = pack_bf2(p[12], p[13]), pk7 = pack_bf2(p[14], p[15]);
        ((uint2*)&Pl[pr][qh][2 * pw    ][0][col])[h1] = make_uint2(pk0, pk1);
        ((uint2*)&Pl[pr][qh][2 * pw    ][1][col])[h1] = make_uint2(pk2, pk3);
        ((uint2*)&Pl[pr][qh][2 * pw + 1][0][col])[h1] = make_uint2(pk4, pk5);
        ((uint2*)&Pl[pr][qh][2 * pw + 1][1][col])[h1] = make_uint2(pk6, pk7);
    };

    // produce P(s) from ukh/ukl (=K(s)); reloads ukh/ukl = K(s+1) mid-way.
    auto produce = [&](int s) {
        const int pr = s & 1;
        bf16x8 akh = __builtin_bit_cast(bf16x8, ukh);
        bf16x8 akl = __builtin_bit_cast(bf16x8, ukl);
        // qh = 0
        {
            bf16x8 bh = __builtin_bit_cast(bf16x8, ubqh[0]);
            bf16x8 bl = __builtin_bit_cast(bf16x8, ubql[0]);
            f32x16 e = {0,0,0,0,0,0,0,0,0,0,0,0,0,0,0,0};
            e = __builtin_amdgcn_mfma_f32_32x32x16_bf16(akh, bh, e, 0, 0, 0);
            e = __builtin_amdgcn_mfma_f32_32x32x16_bf16(akl, bh, e, 0, 0, 0);
            e = __builtin_amdgcn_mfma_f32_32x32x16_bf16(akh, bl, e, 0, 0, 0);
            sm_store(e, pr, 0);
        }
        // qh = 1 (+ next-K reload after last akh/akl use)
        {
            bf16x8 bh = __builtin_bit_cast(bf16x8, ubqh[1]);
            bf16x8 bl = __builtin_bit_cast(bf16x8, ubql[1]);
            f32x16 e = {0,0,0,0,0,0,0,0,0,0,0,0,0,0,0,0};
            e = __builtin_amdgcn_mfma_f32_32x32x16_bf16(akh, bh, e, 0, 0, 0);
            e = __builtin_amdgcn_mfma_f32_32x32x16_bf16(akl, bh, e, 0, 0, 0);
            e = __builtin_amdgcn_mfma_f32_32x32x16_bf16(akh, bl, e, 0, 0, 0);
            const int sn = (s < 15) ? s + 1 : s;
            ukh = *(const uint4*)(kbase + (size_t)sn * 8192);
            ukl = *(const uint4*)(kbase + (size_t)sn * 8192 + 512);
            sm_store(e, pr, 1);
        }
    };

    // ---- prologue (convergent barrier after) ----
    if (producer) {
#pragma unroll
        for (int qh = 0; qh < 2; ++qh) {
            const uint16_t* qrow = Qb + ((size_t)(b * 4096 + n0q + qh * 32 + col)) * 32;
            ubqh[qh] = *(const uint4*)(qrow + h1 * 8);
            ubql[qh] = *(const uint4*)(qrow + 16 + h1 * 8);
        }
        kbase = Kb2 + (size_t)b * 131072 + (size_t)pw * 1024 + (size_t)lane * 8;
        ukh = *(const uint4*)(kbase);
        ukl = *(const uint4*)(kbase + 512);
        produce(0);                        // writes Pl[0]; leaves ukh=K(1)
    } else {
        vlane = Vb + (size_t)(b * 8 + pw) * 131072
                   + (size_t)h1 * 256 + (size_t)col * 8;
    }
    __syncthreads();                       // barrier 0 (top level)

    // ---- main loop: one top-level barrier per superstep ----
    for (int ss = 0; ss < 16; ++ss) {
        const int par = ss & 1;
        if (producer) {
            if (ss < 15) produce(ss + 1);  // uses K(ss+1), writes Pl[par^1]
        } else {
            const uint16_t* vss = vlane + (size_t)ss * 8192;
            uint4 vr[8];
            // batch A: frags 0-7
#pragma unroll
            for (int f = 0; f < 8; ++f) vr[f] = *(const uint4*)(vss + f * 512);
            __builtin_amdgcn_s_setprio(1);
#pragma unroll
            for (int f = 0; f < 8; ++f) {
                uint4 pb0 = Pl[par][0][f][h1][col];
                uint4 pb1 = Pl[par][1][f][h1][col];
                acc0 = __builtin_amdgcn_mfma_f32_32x32x16_bf16(
                    __builtin_bit_cast(bf16x8, vr[f]), __builtin_bit_cast(bf16x8, pb0), acc0, 0, 0, 0);
                acc1 = __builtin_amdgcn_mfma_f32_32x32x16_bf16(
                    __builtin_bit_cast(bf16x8, vr[f]), __builtin_bit_cast(bf16x8, pb1), acc1, 0, 0, 0);
            }
            __builtin_amdgcn_s_setprio(0);
            // batch B: frags 8-15 (reuse vr; in-order issue makes WAR safe)
#pragma unroll
            for (int f = 0; f < 8; ++f) vr[f] = *(const uint4*)(vss + (8 + f) * 512);
            __builtin_amdgcn_s_setprio(1);
#pragma unroll
            for (int f = 0; f < 8; ++f) {
                uint4 pb0 = Pl[par][0][8 + f][h1][col];
                uint4 pb1 = Pl[par][1][8 + f][h1][col];
                acc0 = __builtin_amdgcn_mfma_f32_32x32x16_bf16(
                    __builtin_bit_cast(bf16x8, vr[f]), __builtin_bit_cast(bf16x8, pb0), acc0, 0, 0, 0);
                acc1 = __builtin_amdgcn_mfma_f32_32x32x16_bf16(
                    __builtin_bit_cast(bf16x8, vr[f]), __builtin_bit_cast(bf16x8, pb1), acc1, 0, 0, 0);
            }
            __builtin_amdgcn_s_setprio(0);
#pragma unroll
            for (int j = 0; j < 16; ++j) {
                l0 += Ls[par][0][j][col];
                l1 += Ls[par][1][j][col];
            }
        }
        __syncthreads();                   // barriers 1..16 (top level)
    }

    // ---- epilogue (consumers): out = gamma * acc/l + deep ----
    if (!producer) {
        const float g   = gamma[0];
        const float gr0 = g / l0;
        const float gr1 = g / l1;
#pragma unroll
        for (int r = 0; r < 16; ++r) {
            const int crow = (r & 3) + 8 * (r >> 2) + 4 * h1;
            const int chan = pw * 32 + crow;
            size_t i0 = (size_t)(b * 256 + chan) * 4096 + n0q + col;
            out[i0] = fmaf(gr0, acc0[r], deep[i0]);
            size_t i1 = i0 + 32;
            out[i1] = fmaf(gr1, acc1[r], deep[i1]);
        }
    }
}

extern "C" void kernel_launch(void* const* d_in, const int* in_sizes, int n_in,
                              void* d_out, int out_size, void* d_ws, size_t ws_size,
                              hipStream_t stream) {
    const float* deep    = (const float*)d_in[0];
    const float* shallow = (const float*)d_in[1];
    const float* Wq      = (const float*)d_in[2];
    const float* bq      = (const float*)d_in[3];
    const float* Wk      = (const float*)d_in[4];
    const float* bk      = (const float*)d_in[5];
    const float* gamma   = (const float*)d_in[6];
    float* out = (float*)d_out;

    // ws layout: Vb swizzled bf16 (8 MiB) | Qb (1 MiB) | Kb2 (1 MiB)
    uint16_t* Vb  = (uint16_t*)d_ws;
    uint16_t* Qb  = (uint16_t*)((char*)d_ws + (size_t)8 * 1024 * 1024);
    uint16_t* Kb2 = (uint16_t*)((char*)d_ws + (size_t)9 * 1024 * 1024);

    hipLaunchKernelGGL(prepass, dim3(2112), dim3(256), 0, stream,
                       deep, shallow, Wq, bq, Wk, bk, Vb, Qb, Kb2);
    hipLaunchKernelGGL(attn_main, dim3(256), dim3(1024), 0, stream,
                       Qb, Kb2, Vb, deep, gamma, out);
}

// Round 8
// 86.587 us; speedup vs baseline: 2.8130x; 1.0036x over previous
//
#include <hip/hip_runtime.h>
#include <hip/hip_bf16.h>
#include <stdint.h>

// Problem constants: B=4, deep_C=256, shallow_C=64, H=W=64, N=4096, qk_C=16.
#define LOG2E 1.44269504088896340736f

typedef __bf16 bf16x8 __attribute__((ext_vector_type(8)));
typedef float  f32x16 __attribute__((ext_vector_type(16)));

__device__ __forceinline__ uint32_t pack_bf2(float a, float b) {
    __bf16 ba = (__bf16)a;  // RNE
    __bf16 bb = (__bf16)b;
    uint16_t ua = __builtin_bit_cast(uint16_t, ba);
    uint16_t ub = __builtin_bit_cast(uint16_t, bb);
    return (uint32_t)ua | ((uint32_t)ub << 16);
}

// ---------------- Fused prepass: qk (blocks 0..63) + vconv (64..2111) ----
// Vb unit (16 B = 8 keys x 1 chan): gid = (((b*8+ct)*256+kb)*2+h1)*32+c
//   holds deep[b][ct*32+c][kb*16+h1*8 .. +7] as bf16.
// Qb rows: [b][n][32 bf16] = [hi c0..15 | lo c0..15], q PRE-SCALED by LOG2E.
// Kb2 units: addr_u16 = b*131072 + (n>>5)*1024 + s*512 + (h1*32+(n&31))*8,
//   s=0 hi / 1 lo  (a wave reads 1 KB contiguous per frag pair).
__global__ void __launch_bounds__(256) prepass(
    const float* __restrict__ deep, const float* __restrict__ shallow,
    const float* __restrict__ Wq, const float* __restrict__ bq,
    const float* __restrict__ Wk, const float* __restrict__ bk,
    uint16_t* __restrict__ Vb, uint16_t* __restrict__ Qb,
    uint16_t* __restrict__ Kb2) {
    const int blk = blockIdx.x;
    if (blk < 64) {
        int gid = blk * 256 + threadIdx.x;  // 0..16383 = b*4096+n
        int b = gid >> 12;
        int n = gid & 4095;
        const float* sp = shallow + (size_t)b * 64 * 4096 + n;
        float q[16], k[16];
#pragma unroll
        for (int o = 0; o < 16; ++o) { q[o] = bq[o]; k[o] = bk[o]; }
#pragma unroll 4
        for (int c = 0; c < 64; ++c) {
            float s = sp[(size_t)c * 4096];
#pragma unroll
            for (int o = 0; o < 16; ++o) {
                q[o] = fmaf(Wq[o * 64 + c], s, q[o]);
                k[o] = fmaf(Wk[o * 64 + c], s, k[o]);
            }
        }
        uint16_t* qr = Qb + (size_t)gid * 32;
        float klo[16];
#pragma unroll
        for (int o = 0; o < 16; ++o) {
            float qs = q[o] * LOG2E;             // fold log2(e) into Q
            __bf16 qh = (__bf16)qs; float qhf = (float)qh;
            __bf16 ql = (__bf16)(qs - qhf);
            qr[o]      = __builtin_bit_cast(uint16_t, qh);
            qr[16 + o] = __builtin_bit_cast(uint16_t, ql);
            klo[o] = k[o] - (float)((__bf16)k[o]);
        }
        uint16_t* kbase = Kb2 + (size_t)b * 131072 + (size_t)(n >> 5) * 1024
                              + (size_t)(n & 31) * 8;
        *(uint4*)(kbase +   0) = make_uint4(pack_bf2(k[0], k[1]),   pack_bf2(k[2], k[3]),
                                            pack_bf2(k[4], k[5]),   pack_bf2(k[6], k[7]));
        *(uint4*)(kbase + 256) = make_uint4(pack_bf2(k[8], k[9]),   pack_bf2(k[10], k[11]),
                                            pack_bf2(k[12], k[13]), pack_bf2(k[14], k[15]));
        *(uint4*)(kbase + 512) = make_uint4(pack_bf2(klo[0], klo[1]),   pack_bf2(klo[2], klo[3]),
                                            pack_bf2(klo[4], klo[5]),   pack_bf2(klo[6], klo[7]));
        *(uint4*)(kbase + 768) = make_uint4(pack_bf2(klo[8], klo[9]),   pack_bf2(klo[10], klo[11]),
                                            pack_bf2(klo[12], klo[13]), pack_bf2(klo[14], klo[15]));
    } else {
        int gid = (blk - 64) * 256 + threadIdx.x;   // 0..524287
        int c  = gid & 31;
        int h1 = (gid >> 5) & 1;
        int kb = (gid >> 6) & 255;
        int ct = (gid >> 14) & 7;
        int b  = gid >> 17;
        int chan = ct * 32 + c;
        int key  = kb * 16 + h1 * 8;
        const float4* dp = (const float4*)(deep + ((size_t)(b * 256 + chan) * 4096 + key));
        float4 f0 = dp[0], f1 = dp[1];
        ((uint4*)Vb)[gid] = make_uint4(pack_bf2(f0.x, f0.y), pack_bf2(f0.z, f0.w),
                                       pack_bf2(f1.x, f1.y), pack_bf2(f1.z, f1.w));
    }
}

// ---------------- Main fused flash-attention kernel ----------------------
// Grid: 256 blocks x 768 threads (12 waves, 3/SIMD). Block = (b, 64-query
// tile), all 256 chans. Single loop, ALL barriers top-level (convergent).
//   waves 0-7 (producers): QK^T + max-free softmax for their 32-key slice
//     of superstep ss+1 -> Pl[(ss+1)&1], Ls.
//   waves 8-11 (consumers): 2x2 register-blocked PV — each wave owns
//     2 chan-tiles x 2 query-halves (4 accs), so every LDS P-frag read and
//     every L2 V-frag load feeds 2 MFMAs (halves LDS traffic vs r7, which
//     was the measured ~3k cy/ss bottleneck). V ping-pong batched (4 frags
//     x 2 ct per batch) with cross-superstep prefetch of batch 0.
// Per SIMD: 2 producers (VALU/trans/ds_write) + 1 consumer (MFMA/ds_read/L2)
// — disjoint pipes overlap.
__global__ void __launch_bounds__(768, 3) attn_main(
    const uint16_t* __restrict__ Qb, const uint16_t* __restrict__ Kb2,
    const uint16_t* __restrict__ Vb, const float* __restrict__ deep,
    const float* __restrict__ gamma, float* __restrict__ out) {
    const int lane = threadIdx.x & 63;
    const int w    = threadIdx.x >> 6;   // 0..11
    const int col  = lane & 31;
    const int h1   = lane >> 5;
    const bool producer = (w < 8);
    const int  pw = w;                   // producer key-slice (0..7)
    const int  cw = w - 8;               // consumer chan-pair (0..3)

    // XCD-locality: one batch per XCD pair (V slice 2 MB < 4 MB L2/XCD).
    const int bid = blockIdx.x;
    const int xcd = bid & 7;
    const int b   = xcd >> 1;
    const int qt  = ((bid >> 3) << 1) + (xcd & 1);   // 0..63
    const int n0q = qt * 64;

    __shared__ uint4 Pl[2][2][16][2][32];  // par, qh, frag, h1', col  = 64 KB
    __shared__ float Ls[2][2][16][32];     // par, qh, pw*2+h1, col    =  8 KB

    // ---- role state ----
    uint4 ubqh[2], ubql[2];                // producer: Q B-frags (log2-scaled)
    uint4 ukh, ukl;                        // producer: K frags
    const uint16_t* kbase = nullptr;
    const uint16_t* vl0 = nullptr;         // consumer: V rows for ct0 = 2cw
    const uint16_t* vl1 = nullptr;         //           and ct1 = 2cw+1
    f32x16 accA = {0,0,0,0,0,0,0,0,0,0,0,0,0,0,0,0};  // (ct0,qh0)
    f32x16 accB = {0,0,0,0,0,0,0,0,0,0,0,0,0,0,0,0};  // (ct0,qh1)
    f32x16 accC = {0,0,0,0,0,0,0,0,0,0,0,0,0,0,0,0};  // (ct1,qh0)
    f32x16 accD = {0,0,0,0,0,0,0,0,0,0,0,0,0,0,0,0};  // (ct1,qh1)
    float l0 = 0.0f, l1 = 0.0f;
    uint4 vA[8], vB[8];                    // V ping-pong (4 frags x 2 ct each)

    auto sm_store = [&](const f32x16& e, int pr, int qh) {
        float p[16];
#pragma unroll
        for (int r = 0; r < 16; ++r) p[r] = exp2f(e[r]);   // Q pre-scaled
        float t0 = (p[0] + p[1]) + (p[2] + p[3]);
        float t1 = (p[4] + p[5]) + (p[6] + p[7]);
        float t2 = (p[8] + p[9]) + (p[10] + p[11]);
        float t3 = (p[12] + p[13]) + (p[14] + p[15]);
        Ls[pr][qh][pw * 2 + h1][col] = (t0 + t1) + (t2 + t3);
        uint32_t pk0 = pack_bf2(p[0],  p[1]),  pk1 = pack_bf2(p[2],  p[3]);
        uint32_t pk2 = pack_bf2(p[4],  p[5]),  pk3 = pack_bf2(p[6],  p[7]);
        uint32_t pk4 = pack_bf2(p[8],  p[9]),  pk5 = pack_bf2(p[10], p[11]);
        uint32_t pk6 = pack_bf2(p[12], p[13]), pk7 = pack_bf2(p[14], p[15]);
        ((uint2*)&Pl[pr][qh][2 * pw    ][0][col])[h1] = make_uint2(pk0, pk1);
        ((uint2*)&Pl[pr][qh][2 * pw    ][1][col])[h1] = make_uint2(pk2, pk3);
        ((uint2*)&Pl[pr][qh][2 * pw + 1][0][col])[h1] = make_uint2(pk4, pk5);
        ((uint2*)&Pl[pr][qh][2 * pw + 1][1][col])[h1] = make_uint2(pk6, pk7);
    };

    // produce P(s) from ukh/ukl (=K(s)); reloads ukh/ukl = K(s+1) mid-way.
    auto produce = [&](int s) {
        const int pr = s & 1;
        bf16x8 akh = __builtin_bit_cast(bf16x8, ukh);
        bf16x8 akl = __builtin_bit_cast(bf16x8, ukl);
        {
            bf16x8 bh = __builtin_bit_cast(bf16x8, ubqh[0]);
            bf16x8 bl = __builtin_bit_cast(bf16x8, ubql[0]);
            f32x16 e = {0,0,0,0,0,0,0,0,0,0,0,0,0,0,0,0};
            e = __builtin_amdgcn_mfma_f32_32x32x16_bf16(akh, bh, e, 0, 0, 0);
            e = __builtin_amdgcn_mfma_f32_32x32x16_bf16(akl, bh, e, 0, 0, 0);
            e = __builtin_amdgcn_mfma_f32_32x32x16_bf16(akh, bl, e, 0, 0, 0);
            sm_store(e, pr, 0);
        }
        {
            bf16x8 bh = __builtin_bit_cast(bf16x8, ubqh[1]);
            bf16x8 bl = __builtin_bit_cast(bf16x8, ubql[1]);
            f32x16 e = {0,0,0,0,0,0,0,0,0,0,0,0,0,0,0,0};
            e = __builtin_amdgcn_mfma_f32_32x32x16_bf16(akh, bh, e, 0, 0, 0);
            e = __builtin_amdgcn_mfma_f32_32x32x16_bf16(akl, bh, e, 0, 0, 0);
            e = __builtin_amdgcn_mfma_f32_32x32x16_bf16(akh, bl, e, 0, 0, 0);
            const int sn = (s < 15) ? s + 1 : s;
            ukh = *(const uint4*)(kbase + (size_t)sn * 8192);
            ukl = *(const uint4*)(kbase + (size_t)sn * 8192 + 512);
            sm_store(e, pr, 1);
        }
    };

// consumer helpers (constant indices only — full unroll)
#define LOADB(buf, v0p, v1p, bt)                                          \
    {                                                                     \
        _Pragma("unroll")                                                 \
        for (int q = 0; q < 4; ++q) {                                     \
            buf[q]     = *(const uint4*)((v0p) + ((bt) * 4 + q) * 512);   \
            buf[4 + q] = *(const uint4*)((v1p) + ((bt) * 4 + q) * 512);   \
        }                                                                 \
    }
#define MFMAB(buf, bt, par)                                               \
    {                                                                     \
        __builtin_amdgcn_s_setprio(1);                                    \
        _Pragma("unroll")                                                 \
        for (int q = 0; q < 4; ++q) {                                     \
            const int f = (bt) * 4 + q;                                   \
            uint4 pb0 = Pl[par][0][f][h1][col];                           \
            uint4 pb1 = Pl[par][1][f][h1][col];                           \
            bf16x8 a0 = __builtin_bit_cast(bf16x8, buf[q]);               \
            bf16x8 a1 = __builtin_bit_cast(bf16x8, buf[4 + q]);           \
            bf16x8 p0 = __builtin_bit_cast(bf16x8, pb0);                  \
            bf16x8 p1 = __builtin_bit_cast(bf16x8, pb1);                  \
            accA = __builtin_amdgcn_mfma_f32_32x32x16_bf16(a0, p0, accA, 0, 0, 0); \
            accB = __builtin_amdgcn_mfma_f32_32x32x16_bf16(a0, p1, accB, 0, 0, 0); \
            accC = __builtin_amdgcn_mfma_f32_32x32x16_bf16(a1, p0, accC, 0, 0, 0); \
            accD = __builtin_amdgcn_mfma_f32_32x32x16_bf16(a1, p1, accD, 0, 0, 0); \
        }                                                                 \
        __builtin_amdgcn_s_setprio(0);                                    \
    }

    // ---- prologue (convergent barrier after) ----
    if (producer) {
#pragma unroll
        for (int qh = 0; qh < 2; ++qh) {
            const uint16_t* qrow = Qb + ((size_t)(b * 4096 + n0q + qh * 32 + col)) * 32;
            ubqh[qh] = *(const uint4*)(qrow + h1 * 8);
            ubql[qh] = *(const uint4*)(qrow + 16 + h1 * 8);
        }
        kbase = Kb2 + (size_t)b * 131072 + (size_t)pw * 1024 + (size_t)lane * 8;
        ukh = *(const uint4*)(kbase);
        ukl = *(const uint4*)(kbase + 512);
        produce(0);                        // writes Pl[0]; leaves ukh=K(1)
    } else {
        vl0 = Vb + (size_t)(b * 8 + cw * 2) * 131072
                 + (size_t)h1 * 256 + (size_t)col * 8;
        vl1 = vl0 + 131072;
        LOADB(vA, vl0, vl1, 0);            // batch 0 of ss=0 (drains at barrier)
    }
    __syncthreads();                       // barrier 0 (top level)

    // ---- main loop: one top-level barrier per superstep ----
    for (int ss = 0; ss < 16; ++ss) {
        const int par = ss & 1;
        if (producer) {
            if (ss < 15) produce(ss + 1);  // uses K(ss+1), writes Pl[par^1]
        } else {
            const uint16_t* v0 = vl0 + (size_t)ss * 8192;
            const uint16_t* v1 = vl1 + (size_t)ss * 8192;
            LOADB(vB, v0, v1, 1);
            MFMAB(vA, 0, par);
            LOADB(vA, v0, v1, 2);
            MFMAB(vB, 1, par);
            LOADB(vB, v0, v1, 3);
            MFMAB(vA, 2, par);
            if (ss < 15) {                 // cross-ss prefetch of batch 0
                const uint16_t* v0n = vl0 + (size_t)(ss + 1) * 8192;
                const uint16_t* v1n = vl1 + (size_t)(ss + 1) * 8192;
                LOADB(vA, v0n, v1n, 0);
            }
            MFMAB(vB, 3, par);
#pragma unroll
            for (int j = 0; j < 16; ++j) {
                l0 += Ls[par][0][j][col];
                l1 += Ls[par][1][j][col];
            }
        }
        __syncthreads();                   // barriers 1..16 (top level)
    }

    // ---- epilogue (consumers): out = gamma * acc/l + deep ----
    if (!producer) {
        const float g   = gamma[0];
        const float gr0 = g / l0;          // qh0 queries
        const float gr1 = g / l1;          // qh1 queries
#pragma unroll
        for (int r = 0; r < 16; ++r) {
            const int crow = (r & 3) + 8 * (r >> 2) + 4 * h1;
            const int ch0  = cw * 64 + crow;        // ct0 = 2cw
            const int ch1  = cw * 64 + 32 + crow;   // ct1 = 2cw+1
            size_t iA = (size_t)(b * 256 + ch0) * 4096 + n0q + col;
            out[iA] = fmaf(gr0, accA[r], deep[iA]);
            size_t iB = iA + 32;
            out[iB] = fmaf(gr1, accB[r], deep[iB]);
            size_t iC = (size_t)(b * 256 + ch1) * 4096 + n0q + col;
            out[iC] = fmaf(gr0, accC[r], deep[iC]);
            size_t iD = iC + 32;
            out[iD] = fmaf(gr1, accD[r], deep[iD]);
        }
    }
#undef LOADB
#undef MFMAB
}

extern "C" void kernel_launch(void* const* d_in, const int* in_sizes, int n_in,
                              void* d_out, int out_size, void* d_ws, size_t ws_size,
                              hipStream_t stream) {
    const float* deep    = (const float*)d_in[0];
    const float* shallow = (const float*)d_in[1];
    const float* Wq      = (const float*)d_in[2];
    const float* bq      = (const float*)d_in[3];
    const float* Wk      = (const float*)d_in[4];
    const float* bk      = (const float*)d_in[5];
    const float* gamma   = (const float*)d_in[6];
    float* out = (float*)d_out;

    // ws layout: Vb swizzled bf16 (8 MiB) | Qb (1 MiB) | Kb2 (1 MiB)
    uint16_t* Vb  = (uint16_t*)d_ws;
    uint16_t* Qb  = (uint16_t*)((char*)d_ws + (size_t)8 * 1024 * 1024);
    uint16_t* Kb2 = (uint16_t*)((char*)d_ws + (size_t)9 * 1024 * 1024);

    hipLaunchKernelGGL(prepass, dim3(2112), dim3(256), 0, stream,
                       deep, shallow, Wq, bq, Wk, bk, Vb, Qb, Kb2);
    hipLaunchKernelGGL(attn_main, dim3(256), dim3(768), 0, stream,
                       Qb, Kb2, Vb, deep, gamma, out);
}